// Round 14
// baseline (1353.397 us; speedup 1.0000x reference)
//
#include <hip/hip_runtime.h>
#include <math.h>

#define TT 50
#define MM 128
#define PP 128
#define FF 64
#define NB 4
#define NTHR 512
#define BN_EPS 1e-5f

typedef unsigned int   u32;
typedef unsigned short u16;
typedef _Float16 f16x8 __attribute__((ext_vector_type(8)));
typedef float    f32x4 __attribute__((ext_vector_type(4)));

#define MFMA16(a, b, c) __builtin_amdgcn_mfma_f32_16x16x32_f16((a), (b), (c), 0, 0, 0)

__device__ __forceinline__ float fsig(float x)  { return 1.0f / (1.0f + __expf(-x)); }
__device__ __forceinline__ float ftanh(float x) { return 1.0f - 2.0f / (__expf(2.0f * x) + 1.0f); }
__device__ __forceinline__ u16 f2h(float x) { _Float16 h = (_Float16)x; u16 r; __builtin_memcpy(&r, &h, 2); return r; }
__device__ __forceinline__ float h2f(u16 u) { _Float16 h; __builtin_memcpy(&h, &u, 2); return (float)h; }

// LDS-only barrier (R9 win): drains lgkmcnt but NOT vmcnt, so global weight
// loads stay in flight across phase boundaries.
__device__ __forceinline__ void lds_barrier() {
    asm volatile("s_waitcnt lgkmcnt(0)\n\ts_barrier" ::: "memory");
}

// ---------------- weight fragment pre-pack (fp16, MFMA A-operand order) ----------
__global__ __launch_bounds__(256) void packA_k(const float* __restrict__ w1, u16* __restrict__ dst) {
    int i = blockIdx.x * 256 + threadIdx.x;
    if (i >= 8 * 8 * 64 * 8) return;                    // 32768
    int j = i & 7, l = (i >> 3) & 63, ks = (i >> 9) & 7, tile = i >> 12;
    int row = tile * 16 + (l & 15);
    int k = ks * 32 + ((l >> 4) & 3) * 8 + j;           // k<256 -> [w1_d | w1_c]
    dst[i] = f2h(w1[row * 384 + k]);
}
__global__ __launch_bounds__(256) void packE_k(const float* __restrict__ fcw, u16* __restrict__ dst) {
    int i = blockIdx.x * 256 + threadIdx.x;
    if (i >= 4 * 6 * 64 * 8) return;                    // 12288
    int j = i & 7, l = (i >> 3) & 63, r = i >> 9;
    int ks = r % 6, tile = r / 6;
    int row = tile * 16 + (l & 15);
    int k = ks * 32 + ((l >> 4) & 3) * 8 + j;           // k<192 -> [ctx | yt]
    dst[i] = f2h(fcw[row * 192 + k]);
}
// pF/pG: frag index = wv*NF + ks*4 + g, gate-interleaved rows (R9 win).
__global__ __launch_bounds__(256) void packF_k(const float* __restrict__ wih0, const float* __restrict__ whh0,
                                               u16* __restrict__ dst) {
    int i = blockIdx.x * 256 + threadIdx.x;
    if (i >= 8 * 24 * 64 * 8) return;                   // 98304
    int j = i & 7, l = (i >> 3) & 63, rem = i >> 9;     // rem 0..191
    int wv = rem / 24, t = rem % 24, ks = t >> 2, g = t & 3;
    int row = g * 128 + wv * 16 + (l & 15);             // gate-interleaved
    int k = ks * 32 + ((l >> 4) & 3) * 8 + j;           // k<192: [ytil(64) | h0(128)]
    float v = (k < 64) ? wih0[row * 64 + k] : whh0[row * 128 + (k - 64)];
    dst[i] = f2h(v);
}
__global__ __launch_bounds__(256) void packG_k(const float* __restrict__ wih1, const float* __restrict__ whh1,
                                               u16* __restrict__ dst) {
    int i = blockIdx.x * 256 + threadIdx.x;
    if (i >= 8 * 32 * 64 * 8) return;                   // 131072
    int j = i & 7, l = (i >> 3) & 63, rem = i >> 9;     // rem 0..255
    int wv = rem >> 5, t = rem & 31, ks = t >> 2, g = t & 3;
    int row = g * 128 + wv * 16 + (l & 15);             // gate-interleaved
    int k = ks * 32 + ((l >> 4) & 3) * 8 + j;           // k<256: [h0new(128) | h1old(128)]
    float v = (k < 128) ? wih1[row * 128 + k] : whh1[row * 128 + (k - 128)];
    dst[i] = f2h(v);
}

// ---- main fused decoder (R12 base + recurrent-half hoisting into phase A) -------
// F = wih0@ytil + whh0@h0_old ; G = wih1@h0_new + whh1@h1_old.
// The @h0_old/@h1_old halves depend only on LAST step's outputs -> compute them
// in phase A (idle MFMA pipe there), carry in persistent facc/gacc registers.
// On-path F: 8 MFMAs (prefetched fw0); on-path G: 16 MFMAs. 32 L2 frag-load
// latencies move off the critical chain. Register-neutral vs R12: fw0 prefetch
// moved D->E (after ew dies), gw0 prefetch dropped.
__global__ __launch_bounds__(NTHR, 2) void decoder_kernel(
    const float* __restrict__ X,      // (B,T,M) f32
    const float* __restrict__ yprev,  // (B,T,F) f32
    const float* __restrict__ w1,     // (128,384) f32 (xp prologue only)
    const float* __restrict__ b1,
    const float* __restrict__ w2,
    const float* __restrict__ b2,
    const float* __restrict__ fcb,
    const float* __restrict__ bng,
    const float* __restrict__ bnb,
    const float* __restrict__ bnm,
    const float* __restrict__ bnv,
    const float* __restrict__ bih0,
    const float* __restrict__ bhh0,
    const float* __restrict__ bih1,
    const float* __restrict__ bhh1,
    const float* __restrict__ fcfw,   // (64,256) f32 (epilogue)
    const float* __restrict__ fcfb,
    const u16* __restrict__ pA,       // packed frags
    const u16* __restrict__ pE,
    const u16* __restrict__ pF,
    const u16* __restrict__ pG,
    float* __restrict__ out)          // (B,64)
{
    __shared__ __align__(16) u16   Xh[NB][TT][136];      // fp16 X tile
    __shared__ __align__(16) u16   xph[NB][TT][140];     // fp16 x_proj
    __shared__ __align__(16) u16   h0h[2][NB][144];
    __shared__ __align__(16) u16   h1h[2][NB][144];
    __shared__ __align__(16) u16   c1h[NB][144];
    __shared__ __align__(16) u16   ytilh[NB][72];
    __shared__ __align__(16) u16   ctyh[NB][200];        // [ctx(128) | yt(64)]
    __shared__ __align__(16) float spf[NB][132];
    __shared__ __align__(16) float c0f[NB][132], c1f[NB][132];
    __shared__ __align__(16) float scs[NB][68];
    __shared__ __align__(16) float b1s[128], w2s[128];
    __shared__ __align__(16) float fck0s[FF], fck1s[FF];
    __shared__ __align__(16) float bsum0s[512], bsum1s[512];

    const int tid = threadIdx.x;
    const int b0 = blockIdx.x * NB;
    const int wv = tid >> 6, l = tid & 63;
    const int kg = (l >> 4) & 3;      // k-group within wave
    const int c4 = l & 3;             // batch col (duplicated to cols 4-15)
    const int cown = l & 15;          // C-frag col; valid batch iff <4

    // ---- prologue: X -> fp16 LDS ----
    for (int i4 = tid; i4 < NB * TT * 32; i4 += NTHR) {
        int bb = i4 / (TT * 32);
        int r  = i4 % (TT * 32);
        float4 v = ((const float4*)(X + (size_t)(b0 + bb) * TT * MM))[r];
        uint2 pk;
        pk.x = (u32)f2h(v.x) | ((u32)f2h(v.y) << 16);
        pk.y = (u32)f2h(v.z) | ((u32)f2h(v.w) << 16);
        *(uint2*)&Xh[bb][r >> 5][(r & 31) * 4] = pk;
    }
    for (int i = tid; i < NB * 144; i += NTHR) {
        int bb = i / 144, k = i % 144;
        h0h[0][bb][k] = 0; h0h[1][bb][k] = 0;
        h1h[0][bb][k] = 0; h1h[1][bb][k] = 0;
        c1h[bb][k] = 0;
        if (k < 132) { c0f[bb][k] = 0.f; c1f[bb][k] = 0.f; }
    }
    if (tid < 128) { b1s[tid] = b1[tid]; w2s[tid] = w2[tid]; }
    else if (tid < 192) {
        int f = tid - 128;
        float k1 = rsqrtf(bnv[f] + BN_EPS) * bng[f];
        fck1s[f] = k1;
        fck0s[f] = (fcb[f] - bnm[f]) * k1 + bnb[f];
    }
    bsum0s[tid] = bih0[tid] + bhh0[tid];
    bsum1s[tid] = bih1[tid] + bhh1[tid];

    // ---- phase-B ownership + xp prologue (f32 math -> fp16 LDS) ----
    const int bq = tid >> 7, rr = tid & 127;
    const bool own = rr < 2 * TT;
    const int tq = rr >> 1, qq = rr & 1;
    const float b2v = b2[0];

    if (own) {
        float xf[64];
        #pragma unroll
        for (int n = 0; n < 64; ++n) xf[n] = 0.f;
        const float* Xrow = X + ((size_t)(b0 + bq) * TT + tq) * MM;
        for (int m4 = 0; m4 < 32; ++m4) {
            float4 xv = *(const float4*)(Xrow + m4 * 4);
            #pragma unroll
            for (int n = 0; n < 64; ++n) {
                float4 w = *(const float4*)(w1 + (size_t)(qq * 64 + n) * 384 + 256 + m4 * 4);
                xf[n] += xv.x * w.x + xv.y * w.y + xv.z * w.z + xv.w * w.w;
            }
        }
        #pragma unroll
        for (int j = 0; j < 32; ++j) {
            u32 pk = (u32)f2h(xf[2 * j]) | ((u32)f2h(xf[2 * j + 1]) << 16);
            *(u32*)&xph[bq][tq][qq * 64 + 2 * j] = pk;
        }
    }
    __syncthreads();   // prologue touched global->LDS; full sync once

    for (int ts = 0; ts < TT; ++ts) {
        const int p = ts & 1;

        // ---- A (MFMA): sp = w1_dc @ [h1|c1]; PLUS off-path recurrent halves ----
        f32x4 facc0, facc1, facc2, facc3;   // = bsum0 + whh0 @ h0_old
        f32x4 gacc0, gacc1, gacc2, gacc3;   // = bsum1 + whh1 @ h1_old
        {
            f32x4 acc = *(const f32x4*)&b1s[wv * 16 + kg * 4];
            const u16* abase = pA + (size_t)(wv * 8) * 512 + (size_t)l * 8;
            #pragma unroll
            for (int ks = 0; ks < 8; ++ks) {
                f16x8 a = *(const f16x8*)(abase + ks * 512);
                const u16* bp = (ks < 4) ? &h1h[p][c4][ks * 32 + kg * 8]
                                         : &c1h[c4][(ks - 4) * 32 + kg * 8];
                acc = MFMA16(a, *(const f16x8*)bp, acc);
            }
            if (cown < 4) *(f32x4*)&spf[cown][wv * 16 + kg * 4] = acc;
        }
        {   // F_half: whh0 @ h0_old (pF ks 2..5)
            const u16* pwf = pF + (size_t)wv * 24 * 512 + (size_t)l * 8;
            facc0 = *(const f32x4*)&bsum0s[0 * 128 + wv * 16 + kg * 4];
            facc1 = *(const f32x4*)&bsum0s[1 * 128 + wv * 16 + kg * 4];
            facc2 = *(const f32x4*)&bsum0s[2 * 128 + wv * 16 + kg * 4];
            facc3 = *(const f32x4*)&bsum0s[3 * 128 + wv * 16 + kg * 4];
            #pragma unroll
            for (int ks = 2; ks < 6; ++ks) {
                f16x8 b = *(const f16x8*)&h0h[p][c4][(ks - 2) * 32 + kg * 8];
                facc0 = MFMA16(*(const f16x8*)(pwf + (ks * 4 + 0) * 512), b, facc0);
                facc1 = MFMA16(*(const f16x8*)(pwf + (ks * 4 + 1) * 512), b, facc1);
                facc2 = MFMA16(*(const f16x8*)(pwf + (ks * 4 + 2) * 512), b, facc2);
                facc3 = MFMA16(*(const f16x8*)(pwf + (ks * 4 + 3) * 512), b, facc3);
            }
        }
        {   // G_half: whh1 @ h1_old (pG ks 4..7)
            const u16* pwg = pG + (size_t)wv * 32 * 512 + (size_t)l * 8;
            gacc0 = *(const f32x4*)&bsum1s[0 * 128 + wv * 16 + kg * 4];
            gacc1 = *(const f32x4*)&bsum1s[1 * 128 + wv * 16 + kg * 4];
            gacc2 = *(const f32x4*)&bsum1s[2 * 128 + wv * 16 + kg * 4];
            gacc3 = *(const f32x4*)&bsum1s[3 * 128 + wv * 16 + kg * 4];
            #pragma unroll
            for (int ks = 4; ks < 8; ++ks) {
                f16x8 b = *(const f16x8*)&h1h[p][c4][(ks - 4) * 32 + kg * 8];
                gacc0 = MFMA16(*(const f16x8*)(pwg + (ks * 4 + 0) * 512), b, gacc0);
                gacc1 = MFMA16(*(const f16x8*)(pwg + (ks * 4 + 1) * 512), b, gacc1);
                gacc2 = MFMA16(*(const f16x8*)(pwg + (ks * 4 + 2) * 512), b, gacc2);
                gacc3 = MFMA16(*(const f16x8*)(pwg + (ks * 4 + 3) * 512), b, gacc3);
            }
        }
        // prefetch E frags; they ride across the next barriers
        f16x8 ew[6];
        if (wv < 4) {
            const u16* abase = pE + (size_t)(wv * 6) * 512 + (size_t)l * 8;
            #pragma unroll
            for (int ks = 0; ks < 6; ++ks) ew[ks] = *(const f16x8*)(abase + ks * 512);
        }
        lds_barrier();

        // ---- B (VALU): score[t] = sum_n tanh(xp+sp)*w2, vectorized LDS reads ----
        if (own) {
            float acc = 0.f;
            #pragma unroll
            for (int jb = 0; jb < 8; ++jb) {
                int n = qq * 64 + jb * 8;
                uint4 xv  = *(const uint4*)&xph[bq][tq][n];
                f32x4 sp0 = *(const f32x4*)&spf[bq][n];
                f32x4 sp1 = *(const f32x4*)&spf[bq][n + 4];
                f32x4 wv0 = *(const f32x4*)&w2s[n];
                f32x4 wv1 = *(const f32x4*)&w2s[n + 4];
                acc += ftanh(h2f((u16)(xv.x & 0xffffu)) + sp0[0]) * wv0[0];
                acc += ftanh(h2f((u16)(xv.x >> 16))     + sp0[1]) * wv0[1];
                acc += ftanh(h2f((u16)(xv.y & 0xffffu)) + sp0[2]) * wv0[2];
                acc += ftanh(h2f((u16)(xv.y >> 16))     + sp0[3]) * wv0[3];
                acc += ftanh(h2f((u16)(xv.z & 0xffffu)) + sp1[0]) * wv1[0];
                acc += ftanh(h2f((u16)(xv.z >> 16))     + sp1[1]) * wv1[1];
                acc += ftanh(h2f((u16)(xv.w & 0xffffu)) + sp1[2]) * wv1[2];
                acc += ftanh(h2f((u16)(xv.w >> 16))     + sp1[3]) * wv1[3];
            }
            acc += __shfl_xor(acc, 1);
            if (qq == 0) scs[bq][tq] = acc + b2v;
        }
        lds_barrier();

        // ---- C: softmax (4 waves) + y_t load ----
        if (tid < 256) {
            int b = tid >> 6, t = tid & 63;
            float v = (t < TT) ? scs[b][t] : -1e30f;
            float mx = v;
            #pragma unroll
            for (int o = 32; o; o >>= 1) mx = fmaxf(mx, __shfl_xor(mx, o));
            float e = (t < TT) ? __expf(v - mx) : 0.f;
            float s = e;
            #pragma unroll
            for (int o = 32; o; o >>= 1) s += __shfl_xor(s, o);
            if (t < TT) scs[b][t] = e / s;
        } else {
            int i = tid - 256; int bb = i >> 6, f = i & 63;
            ctyh[bb][128 + f] = f2h(yprev[((size_t)(b0 + bb) * TT + ts) * FF + f]);
        }
        lds_barrier();

        // ---- D (VALU): ctx[m] = sum_t beta[t]*X[t][m] ----
        {
            int bb = tid >> 7, m = tid & 127;
            float acc = 0.f;
            #pragma unroll 10
            for (int t = 0; t < TT; ++t) acc += scs[bb][t] * h2f(Xh[bb][t][m]);
            ctyh[bb][m] = f2h(acc);
        }
        lds_barrier();

        // ---- E (MFMA, waves 0-3): z = fcw @ [ctx|yt]; prefetch fw0 (ew dies here) ----
        f16x8 fw0[8];
        {
            const u16* pwf = pF + (size_t)wv * 24 * 512 + (size_t)l * 8;
            #pragma unroll
            for (int q = 0; q < 8; ++q) fw0[q] = *(const f16x8*)(pwf + q * 512);
        }
        if (wv < 4) {
            f32x4 acc = {0.f, 0.f, 0.f, 0.f};
            #pragma unroll
            for (int ks = 0; ks < 6; ++ks) {
                f16x8 b = *(const f16x8*)&ctyh[c4][ks * 32 + kg * 8];
                acc = MFMA16(ew[ks], b, acc);
            }
            if (cown < 4) {
                int row = wv * 16 + kg * 4;
                f32x4 k1 = *(const f32x4*)&fck1s[row];
                f32x4 k0 = *(const f32x4*)&fck0s[row];
                #pragma unroll
                for (int r = 0; r < 4; ++r)
                    ytilh[cown][row + r] = f2h(acc[r] * k1[r] + k0[r]);
            }
        }
        lds_barrier();

        // ---- F (MFMA): g0 = facc + wih0 @ ytil (prefetched) + in-reg lstm0 update ----
        {
            f32x4 a0 = facc0, a1 = facc1, a2 = facc2, a3 = facc3;
            #pragma unroll
            for (int ks = 0; ks < 2; ++ks) {
                f16x8 b = *(const f16x8*)&ytilh[c4][ks * 32 + kg * 8];
                a0 = MFMA16(fw0[ks * 4 + 0], b, a0);
                a1 = MFMA16(fw0[ks * 4 + 1], b, a1);
                a2 = MFMA16(fw0[ks * 4 + 2], b, a2);
                a3 = MFMA16(fw0[ks * 4 + 3], b, a3);
            }
            if (cown < 4) {                             // a0..a3 = i,f,g,o of own cells
                int cb = wv * 16 + kg * 4;
                u32 lo, hi;
                {
                    float gi = fsig(a0[0]), gF = fsig(a1[0]), gG = ftanh(a2[0]), gO = fsig(a3[0]);
                    float cn = gF * c0f[cown][cb + 0] + gi * gG;
                    c0f[cown][cb + 0] = cn;
                    lo = (u32)f2h(gO * ftanh(cn));
                }
                {
                    float gi = fsig(a0[1]), gF = fsig(a1[1]), gG = ftanh(a2[1]), gO = fsig(a3[1]);
                    float cn = gF * c0f[cown][cb + 1] + gi * gG;
                    c0f[cown][cb + 1] = cn;
                    lo |= (u32)f2h(gO * ftanh(cn)) << 16;
                }
                {
                    float gi = fsig(a0[2]), gF = fsig(a1[2]), gG = ftanh(a2[2]), gO = fsig(a3[2]);
                    float cn = gF * c0f[cown][cb + 2] + gi * gG;
                    c0f[cown][cb + 2] = cn;
                    hi = (u32)f2h(gO * ftanh(cn));
                }
                {
                    float gi = fsig(a0[3]), gF = fsig(a1[3]), gG = ftanh(a2[3]), gO = fsig(a3[3]);
                    float cn = gF * c0f[cown][cb + 3] + gi * gG;
                    c0f[cown][cb + 3] = cn;
                    hi |= (u32)f2h(gO * ftanh(cn)) << 16;
                }
                uint2 pk; pk.x = lo; pk.y = hi;
                *(uint2*)&h0h[p ^ 1][cown][cb] = pk;
            }
        }
        lds_barrier();

        // ---- G (MFMA): g1 = gacc + wih1 @ h0new (streamed ks0-3) + lstm1 update ----
        {
            const u16* pw = pG + (size_t)wv * 32 * 512 + (size_t)l * 8;
            f32x4 a0 = gacc0, a1 = gacc1, a2 = gacc2, a3 = gacc3;
            #pragma unroll
            for (int ks = 0; ks < 4; ++ks) {
                f16x8 b = *(const f16x8*)&h0h[p ^ 1][c4][ks * 32 + kg * 8];
                a0 = MFMA16(*(const f16x8*)(pw + (ks * 4 + 0) * 512), b, a0);
                a1 = MFMA16(*(const f16x8*)(pw + (ks * 4 + 1) * 512), b, a1);
                a2 = MFMA16(*(const f16x8*)(pw + (ks * 4 + 2) * 512), b, a2);
                a3 = MFMA16(*(const f16x8*)(pw + (ks * 4 + 3) * 512), b, a3);
            }
            if (cown < 4) {
                int cb = wv * 16 + kg * 4;
                u32 lo, hi, clo, chi;
                {
                    float gi = fsig(a0[0]), gF = fsig(a1[0]), gG = ftanh(a2[0]), gO = fsig(a3[0]);
                    float cn = gF * c1f[cown][cb + 0] + gi * gG;
                    c1f[cown][cb + 0] = cn;
                    clo = (u32)f2h(cn);
                    lo  = (u32)f2h(gO * ftanh(cn));
                }
                {
                    float gi = fsig(a0[1]), gF = fsig(a1[1]), gG = ftanh(a2[1]), gO = fsig(a3[1]);
                    float cn = gF * c1f[cown][cb + 1] + gi * gG;
                    c1f[cown][cb + 1] = cn;
                    clo |= (u32)f2h(cn) << 16;
                    lo  |= (u32)f2h(gO * ftanh(cn)) << 16;
                }
                {
                    float gi = fsig(a0[2]), gF = fsig(a1[2]), gG = ftanh(a2[2]), gO = fsig(a3[2]);
                    float cn = gF * c1f[cown][cb + 2] + gi * gG;
                    c1f[cown][cb + 2] = cn;
                    chi = (u32)f2h(cn);
                    hi  = (u32)f2h(gO * ftanh(cn));
                }
                {
                    float gi = fsig(a0[3]), gF = fsig(a1[3]), gG = ftanh(a2[3]), gO = fsig(a3[3]);
                    float cn = gF * c1f[cown][cb + 3] + gi * gG;
                    c1f[cown][cb + 3] = cn;
                    chi |= (u32)f2h(cn) << 16;
                    hi  |= (u32)f2h(gO * ftanh(cn)) << 16;
                }
                uint2 pk; pk.x = lo; pk.y = hi;
                *(uint2*)&h1h[p ^ 1][cown][cb] = pk;
                uint2 ck; ck.x = clo; ck.y = chi;
                *(uint2*)&c1h[cown][cb] = ck;
            }
        }
        lds_barrier();
    }

    // ---- epilogue: y = relu([h1,ctx] @ fcf_w.T + fcf_b); final h1 in side 0 ----
    if (tid < 256) {
        int f = tid >> 2, bb = tid & 3;
        const float* wr = fcfw + (size_t)f * 256;
        float acc = fcfb[f];
        #pragma unroll 4
        for (int k4 = 0; k4 < 32; ++k4) {
            float4 w = *(const float4*)(wr + k4 * 4);
            acc += w.x * h2f(h1h[0][bb][k4 * 4 + 0]) + w.y * h2f(h1h[0][bb][k4 * 4 + 1])
                 + w.z * h2f(h1h[0][bb][k4 * 4 + 2]) + w.w * h2f(h1h[0][bb][k4 * 4 + 3]);
        }
        #pragma unroll 4
        for (int k4 = 0; k4 < 32; ++k4) {
            float4 w = *(const float4*)(wr + 128 + k4 * 4);
            acc += w.x * h2f(ctyh[bb][k4 * 4 + 0]) + w.y * h2f(ctyh[bb][k4 * 4 + 1])
                 + w.z * h2f(ctyh[bb][k4 * 4 + 2]) + w.w * h2f(ctyh[bb][k4 * 4 + 3]);
        }
        out[(size_t)(b0 + bb) * FF + f] = fmaxf(acc, 0.f);
    }
}

extern "C" void kernel_launch(void* const* d_in, const int* in_sizes, int n_in,
                              void* d_out, int out_size, void* d_ws, size_t ws_size,
                              hipStream_t stream) {
    (void)in_sizes; (void)n_in; (void)out_size; (void)ws_size;
    const float* X    = (const float*)d_in[0];
    const float* yp   = (const float*)d_in[1];
    const float* w1   = (const float*)d_in[2];
    const float* b1   = (const float*)d_in[3];
    const float* w2   = (const float*)d_in[4];
    const float* b2   = (const float*)d_in[5];
    const float* fcw  = (const float*)d_in[6];
    const float* fcb  = (const float*)d_in[7];
    const float* bng  = (const float*)d_in[8];
    const float* bnb  = (const float*)d_in[9];
    const float* bnm  = (const float*)d_in[10];
    const float* bnv  = (const float*)d_in[11];
    const float* wih0 = (const float*)d_in[12];
    const float* whh0 = (const float*)d_in[13];
    const float* bih0 = (const float*)d_in[14];
    const float* bhh0 = (const float*)d_in[15];
    const float* wih1 = (const float*)d_in[16];
    const float* whh1 = (const float*)d_in[17];
    const float* bih1 = (const float*)d_in[18];
    const float* bhh1 = (const float*)d_in[19];
    const float* fcfw = (const float*)d_in[20];
    const float* fcfb = (const float*)d_in[21];
    float* out = (float*)d_out;

    // fragment-packed fp16 weights in d_ws
    u16* pA = (u16*)d_ws;              // 32768
    u16* pE = pA + 32768;              // 12288
    u16* pF = pE + 12288;              // 98304
    u16* pG = pF + 98304;              // 131072  (total 274432 u16 = 549 KB)

    packA_k<<<dim3(32768 / 256), dim3(256), 0, stream>>>(w1, pA);
    packE_k<<<dim3(12288 / 256), dim3(256), 0, stream>>>(fcw, pE);
    packF_k<<<dim3(98304 / 256), dim3(256), 0, stream>>>(wih0, whh0, pF);
    packG_k<<<dim3(131072 / 256), dim3(256), 0, stream>>>(wih1, whh1, pG);

    decoder_kernel<<<dim3(1024 / NB), dim3(NTHR), 0, stream>>>(
        X, yp, w1, b1, w2, b2, fcb, bng, bnb, bnm, bnv,
        bih0, bhh0, bih1, bhh1, fcfw, fcfb, pA, pE, pF, pG, out);
}

// Round 15
// 830.853 us; speedup vs baseline: 1.6289x; 1.6289x over previous
//
#include <hip/hip_runtime.h>
#include <math.h>

#define TT 50
#define MM 128
#define PP 128
#define FF 64
#define NB 4
#define NTHR 512
#define BN_EPS 1e-5f

typedef unsigned int   u32;
typedef unsigned short u16;
typedef _Float16 f16x8 __attribute__((ext_vector_type(8)));
typedef float    f32x4 __attribute__((ext_vector_type(4)));

#define MFMA16(a, b, c) __builtin_amdgcn_mfma_f32_16x16x32_f16((a), (b), (c), 0, 0, 0)

__device__ __forceinline__ float fsig(float x)  { return 1.0f / (1.0f + __expf(-x)); }
__device__ __forceinline__ float ftanh(float x) { return 1.0f - 2.0f / (__expf(2.0f * x) + 1.0f); }
__device__ __forceinline__ u16 f2h(float x) { _Float16 h = (_Float16)x; u16 r; __builtin_memcpy(&r, &h, 2); return r; }
__device__ __forceinline__ float h2f(u16 u) { _Float16 h; __builtin_memcpy(&h, &u, 2); return (float)h; }

// LDS-only barrier (R9 win): drains lgkmcnt but NOT vmcnt, so global weight
// loads stay in flight across phase boundaries.
__device__ __forceinline__ void lds_barrier() {
    asm volatile("s_waitcnt lgkmcnt(0)\n\ts_barrier" ::: "memory");
}

// ---------------- weight fragment pre-pack (fp16, MFMA A-operand order) ----------
__global__ __launch_bounds__(256) void packA_k(const float* __restrict__ w1, u16* __restrict__ dst) {
    int i = blockIdx.x * 256 + threadIdx.x;
    if (i >= 8 * 8 * 64 * 8) return;                    // 32768
    int j = i & 7, l = (i >> 3) & 63, ks = (i >> 9) & 7, tile = i >> 12;
    int row = tile * 16 + (l & 15);
    int k = ks * 32 + ((l >> 4) & 3) * 8 + j;           // k<256 -> [w1_d | w1_c]
    dst[i] = f2h(w1[row * 384 + k]);
}
__global__ __launch_bounds__(256) void packE_k(const float* __restrict__ fcw, u16* __restrict__ dst) {
    int i = blockIdx.x * 256 + threadIdx.x;
    if (i >= 4 * 6 * 64 * 8) return;                    // 12288
    int j = i & 7, l = (i >> 3) & 63, r = i >> 9;
    int ks = r % 6, tile = r / 6;
    int row = tile * 16 + (l & 15);
    int k = ks * 32 + ((l >> 4) & 3) * 8 + j;           // k<192 -> [ctx | yt]
    dst[i] = f2h(fcw[row * 192 + k]);
}
// pF/pG: frag index = wv*NF + ks*4 + g, gate-interleaved rows (R9 win).
__global__ __launch_bounds__(256) void packF_k(const float* __restrict__ wih0, const float* __restrict__ whh0,
                                               u16* __restrict__ dst) {
    int i = blockIdx.x * 256 + threadIdx.x;
    if (i >= 8 * 24 * 64 * 8) return;                   // 98304
    int j = i & 7, l = (i >> 3) & 63, rem = i >> 9;     // rem 0..191
    int wv = rem / 24, t = rem % 24, ks = t >> 2, g = t & 3;
    int row = g * 128 + wv * 16 + (l & 15);             // gate-interleaved
    int k = ks * 32 + ((l >> 4) & 3) * 8 + j;           // k<192: [ytil(64) | h0(128)]
    float v = (k < 64) ? wih0[row * 64 + k] : whh0[row * 128 + (k - 64)];
    dst[i] = f2h(v);
}
__global__ __launch_bounds__(256) void packG_k(const float* __restrict__ wih1, const float* __restrict__ whh1,
                                               u16* __restrict__ dst) {
    int i = blockIdx.x * 256 + threadIdx.x;
    if (i >= 8 * 32 * 64 * 8) return;                   // 131072
    int j = i & 7, l = (i >> 3) & 63, rem = i >> 9;     // rem 0..255
    int wv = rem >> 5, t = rem & 31, ks = t >> 2, g = t & 3;
    int row = g * 128 + wv * 16 + (l & 15);             // gate-interleaved
    int k = ks * 32 + ((l >> 4) & 3) * 8 + j;           // k<256: [h0new(128) | h1old(128)]
    float v = (k < 128) ? wih1[row * 128 + k] : whh1[row * 128 + (k - 128)];
    dst[i] = f2h(v);
}

// ---------------- main fused decoder (R12 + vectorized scs reads in D) ----------
__global__ __launch_bounds__(NTHR, 2) void decoder_kernel(
    const float* __restrict__ X,      // (B,T,M) f32
    const float* __restrict__ yprev,  // (B,T,F) f32
    const float* __restrict__ w1,     // (128,384) f32 (xp prologue only)
    const float* __restrict__ b1,
    const float* __restrict__ w2,
    const float* __restrict__ b2,
    const float* __restrict__ fcb,
    const float* __restrict__ bng,
    const float* __restrict__ bnb,
    const float* __restrict__ bnm,
    const float* __restrict__ bnv,
    const float* __restrict__ bih0,
    const float* __restrict__ bhh0,
    const float* __restrict__ bih1,
    const float* __restrict__ bhh1,
    const float* __restrict__ fcfw,   // (64,256) f32 (epilogue)
    const float* __restrict__ fcfb,
    const u16* __restrict__ pA,       // packed frags
    const u16* __restrict__ pE,
    const u16* __restrict__ pF,
    const u16* __restrict__ pG,
    float* __restrict__ out)          // (B,64)
{
    __shared__ __align__(16) u16   Xh[NB][TT][136];      // fp16 X tile
    __shared__ __align__(16) u16   xph[NB][TT][140];     // fp16 x_proj
    __shared__ __align__(16) u16   h0h[2][NB][144];
    __shared__ __align__(16) u16   h1h[2][NB][144];
    __shared__ __align__(16) u16   c1h[NB][144];
    __shared__ __align__(16) u16   ytilh[NB][72];
    __shared__ __align__(16) u16   ctyh[NB][200];        // [ctx(128) | yt(64)]
    __shared__ __align__(16) float spf[NB][132];
    __shared__ __align__(16) float c0f[NB][132], c1f[NB][132];
    __shared__ __align__(16) float scs[NB][68];
    __shared__ __align__(16) float b1s[128], w2s[128];
    __shared__ __align__(16) float fck0s[FF], fck1s[FF];
    __shared__ __align__(16) float bsum0s[512], bsum1s[512];

    const int tid = threadIdx.x;
    const int b0 = blockIdx.x * NB;
    const int wv = tid >> 6, l = tid & 63;
    const int kg = (l >> 4) & 3;      // k-group within wave
    const int c4 = l & 3;             // batch col (duplicated to cols 4-15)
    const int cown = l & 15;          // C-frag col; valid batch iff <4

    // ---- prologue: X -> fp16 LDS ----
    for (int i4 = tid; i4 < NB * TT * 32; i4 += NTHR) {
        int bb = i4 / (TT * 32);
        int r  = i4 % (TT * 32);
        float4 v = ((const float4*)(X + (size_t)(b0 + bb) * TT * MM))[r];
        uint2 pk;
        pk.x = (u32)f2h(v.x) | ((u32)f2h(v.y) << 16);
        pk.y = (u32)f2h(v.z) | ((u32)f2h(v.w) << 16);
        *(uint2*)&Xh[bb][r >> 5][(r & 31) * 4] = pk;
    }
    for (int i = tid; i < NB * 144; i += NTHR) {
        int bb = i / 144, k = i % 144;
        h0h[0][bb][k] = 0; h0h[1][bb][k] = 0;
        h1h[0][bb][k] = 0; h1h[1][bb][k] = 0;
        c1h[bb][k] = 0;
        if (k < 132) { c0f[bb][k] = 0.f; c1f[bb][k] = 0.f; }
    }
    if (tid < 128) { b1s[tid] = b1[tid]; w2s[tid] = w2[tid]; }
    else if (tid < 192) {
        int f = tid - 128;
        float k1 = rsqrtf(bnv[f] + BN_EPS) * bng[f];
        fck1s[f] = k1;
        fck0s[f] = (fcb[f] - bnm[f]) * k1 + bnb[f];
    }
    bsum0s[tid] = bih0[tid] + bhh0[tid];
    bsum1s[tid] = bih1[tid] + bhh1[tid];

    // ---- phase-B ownership + xp prologue (f32 math -> fp16 LDS) ----
    const int bq = tid >> 7, rr = tid & 127;
    const bool own = rr < 2 * TT;
    const int tq = rr >> 1, qq = rr & 1;
    const float b2v = b2[0];

    if (own) {
        float xf[64];
        #pragma unroll
        for (int n = 0; n < 64; ++n) xf[n] = 0.f;
        const float* Xrow = X + ((size_t)(b0 + bq) * TT + tq) * MM;
        for (int m4 = 0; m4 < 32; ++m4) {
            float4 xv = *(const float4*)(Xrow + m4 * 4);
            #pragma unroll
            for (int n = 0; n < 64; ++n) {
                float4 w = *(const float4*)(w1 + (size_t)(qq * 64 + n) * 384 + 256 + m4 * 4);
                xf[n] += xv.x * w.x + xv.y * w.y + xv.z * w.z + xv.w * w.w;
            }
        }
        #pragma unroll
        for (int j = 0; j < 32; ++j) {
            u32 pk = (u32)f2h(xf[2 * j]) | ((u32)f2h(xf[2 * j + 1]) << 16);
            *(u32*)&xph[bq][tq][qq * 64 + 2 * j] = pk;
        }
    }
    __syncthreads();   // prologue touched global->LDS; full sync once

    for (int ts = 0; ts < TT; ++ts) {
        const int p = ts & 1;

        // ---- A (MFMA): sp = w1_dc @ [h1|c1] ----
        {
            f32x4 acc = *(const f32x4*)&b1s[wv * 16 + kg * 4];
            const u16* abase = pA + (size_t)(wv * 8) * 512 + (size_t)l * 8;
            #pragma unroll
            for (int ks = 0; ks < 8; ++ks) {
                f16x8 a = *(const f16x8*)(abase + ks * 512);
                const u16* bp = (ks < 4) ? &h1h[p][c4][ks * 32 + kg * 8]
                                         : &c1h[c4][(ks - 4) * 32 + kg * 8];
                acc = MFMA16(a, *(const f16x8*)bp, acc);
            }
            if (cown < 4) *(f32x4*)&spf[cown][wv * 16 + kg * 4] = acc;
        }
        // prefetch E frags now; they ride across the next 4 LDS barriers
        f16x8 ew[6];
        if (wv < 4) {
            const u16* abase = pE + (size_t)(wv * 6) * 512 + (size_t)l * 8;
            #pragma unroll
            for (int ks = 0; ks < 6; ++ks) ew[ks] = *(const f16x8*)(abase + ks * 512);
        }
        lds_barrier();

        // ---- B (VALU): score[t] = sum_n tanh(xp+sp)*w2, vectorized LDS reads ----
        if (own) {
            float acc = 0.f;
            #pragma unroll
            for (int jb = 0; jb < 8; ++jb) {
                int n = qq * 64 + jb * 8;
                uint4 xv  = *(const uint4*)&xph[bq][tq][n];
                f32x4 sp0 = *(const f32x4*)&spf[bq][n];
                f32x4 sp1 = *(const f32x4*)&spf[bq][n + 4];
                f32x4 wv0 = *(const f32x4*)&w2s[n];
                f32x4 wv1 = *(const f32x4*)&w2s[n + 4];
                acc += ftanh(h2f((u16)(xv.x & 0xffffu)) + sp0[0]) * wv0[0];
                acc += ftanh(h2f((u16)(xv.x >> 16))     + sp0[1]) * wv0[1];
                acc += ftanh(h2f((u16)(xv.y & 0xffffu)) + sp0[2]) * wv0[2];
                acc += ftanh(h2f((u16)(xv.y >> 16))     + sp0[3]) * wv0[3];
                acc += ftanh(h2f((u16)(xv.z & 0xffffu)) + sp1[0]) * wv1[0];
                acc += ftanh(h2f((u16)(xv.z >> 16))     + sp1[1]) * wv1[1];
                acc += ftanh(h2f((u16)(xv.w & 0xffffu)) + sp1[2]) * wv1[2];
                acc += ftanh(h2f((u16)(xv.w >> 16))     + sp1[3]) * wv1[3];
            }
            acc += __shfl_xor(acc, 1);
            if (qq == 0) scs[bq][tq] = acc + b2v;
        }
        lds_barrier();

        // ---- C: softmax (4 waves) + y_t load ----
        if (tid < 256) {
            int b = tid >> 6, t = tid & 63;
            float v = (t < TT) ? scs[b][t] : -1e30f;
            float mx = v;
            #pragma unroll
            for (int o = 32; o; o >>= 1) mx = fmaxf(mx, __shfl_xor(mx, o));
            float e = (t < TT) ? __expf(v - mx) : 0.f;
            float s = e;
            #pragma unroll
            for (int o = 32; o; o >>= 1) s += __shfl_xor(s, o);
            if (t < TT) scs[b][t] = e / s;
        } else {
            int i = tid - 256; int bb = i >> 6, f = i & 63;
            ctyh[bb][128 + f] = f2h(yprev[((size_t)(b0 + bb) * TT + ts) * FF + f]);
        }
        lds_barrier();

        // ---- D (VALU): ctx[m] = sum_t beta[t]*X[t][m]; scs via f32x4 reads;
        //      prefetch first 8 F frags ----
        f16x8 fw0[8];
        {
            const u16* pw = pF + (size_t)wv * 24 * 512 + (size_t)l * 8;
            #pragma unroll
            for (int q = 0; q < 8; ++q) fw0[q] = *(const f16x8*)(pw + q * 512);
        }
        {
            int bb = tid >> 7, m = tid & 127;
            float acc = 0.f;
            #pragma unroll
            for (int t4 = 0; t4 < 12; ++t4) {
                f32x4 sc = *(const f32x4*)&scs[bb][t4 * 4];
                acc += sc[0] * h2f(Xh[bb][t4 * 4 + 0][m]);
                acc += sc[1] * h2f(Xh[bb][t4 * 4 + 1][m]);
                acc += sc[2] * h2f(Xh[bb][t4 * 4 + 2][m]);
                acc += sc[3] * h2f(Xh[bb][t4 * 4 + 3][m]);
            }
            acc += scs[bb][48] * h2f(Xh[bb][48][m]);
            acc += scs[bb][49] * h2f(Xh[bb][49][m]);
            ctyh[bb][m] = f2h(acc);
        }
        lds_barrier();

        // ---- E (MFMA, waves 0-3): z = fcw @ [ctx|yt]; batchnorm -> ytil ----
        if (wv < 4) {
            f32x4 acc = {0.f, 0.f, 0.f, 0.f};
            #pragma unroll
            for (int ks = 0; ks < 6; ++ks) {
                f16x8 b = *(const f16x8*)&ctyh[c4][ks * 32 + kg * 8];
                acc = MFMA16(ew[ks], b, acc);
            }
            if (cown < 4) {
                int row = wv * 16 + kg * 4;
                f32x4 k1 = *(const f32x4*)&fck1s[row];
                f32x4 k0 = *(const f32x4*)&fck0s[row];
                #pragma unroll
                for (int r = 0; r < 4; ++r)
                    ytilh[cown][row + r] = f2h(acc[r] * k1[r] + k0[r]);
            }
        }
        lds_barrier();

        // ---- F (MFMA, gate-interleaved) + in-register lstm0 update;
        //      prefetch first 8 G frags (fw0 dead after its MFMAs) ----
        f16x8 gw0[8];
        {
            const u16* pw = pF + (size_t)wv * 24 * 512 + (size_t)l * 8;
            f32x4 a0 = *(const f32x4*)&bsum0s[0 * 128 + wv * 16 + kg * 4];
            f32x4 a1 = *(const f32x4*)&bsum0s[1 * 128 + wv * 16 + kg * 4];
            f32x4 a2 = *(const f32x4*)&bsum0s[2 * 128 + wv * 16 + kg * 4];
            f32x4 a3 = *(const f32x4*)&bsum0s[3 * 128 + wv * 16 + kg * 4];
            #pragma unroll
            for (int ks = 0; ks < 2; ++ks) {            // prefetched frags
                f16x8 b = *(const f16x8*)&ytilh[c4][ks * 32 + kg * 8];
                a0 = MFMA16(fw0[ks * 4 + 0], b, a0);
                a1 = MFMA16(fw0[ks * 4 + 1], b, a1);
                a2 = MFMA16(fw0[ks * 4 + 2], b, a2);
                a3 = MFMA16(fw0[ks * 4 + 3], b, a3);
            }
            #pragma unroll
            for (int ks = 2; ks < 6; ++ks) {            // streamed frags
                f16x8 b = *(const f16x8*)&h0h[p][c4][(ks - 2) * 32 + kg * 8];
                a0 = MFMA16(*(const f16x8*)(pw + (ks * 4 + 0) * 512), b, a0);
                a1 = MFMA16(*(const f16x8*)(pw + (ks * 4 + 1) * 512), b, a1);
                a2 = MFMA16(*(const f16x8*)(pw + (ks * 4 + 2) * 512), b, a2);
                a3 = MFMA16(*(const f16x8*)(pw + (ks * 4 + 3) * 512), b, a3);
            }
            {   // G prefetch: first 8 frags (ks 0..1), issued while F finishes
                const u16* pwg = pG + (size_t)wv * 32 * 512 + (size_t)l * 8;
                #pragma unroll
                for (int q = 0; q < 8; ++q) gw0[q] = *(const f16x8*)(pwg + q * 512);
            }
            if (cown < 4) {                             // a0..a3 = i,f,g,o of own cells
                int cb = wv * 16 + kg * 4;
                u32 lo, hi;
                {
                    float gi = fsig(a0[0]), gF = fsig(a1[0]), gG = ftanh(a2[0]), gO = fsig(a3[0]);
                    float cn = gF * c0f[cown][cb + 0] + gi * gG;
                    c0f[cown][cb + 0] = cn;
                    lo = (u32)f2h(gO * ftanh(cn));
                }
                {
                    float gi = fsig(a0[1]), gF = fsig(a1[1]), gG = ftanh(a2[1]), gO = fsig(a3[1]);
                    float cn = gF * c0f[cown][cb + 1] + gi * gG;
                    c0f[cown][cb + 1] = cn;
                    lo |= (u32)f2h(gO * ftanh(cn)) << 16;
                }
                {
                    float gi = fsig(a0[2]), gF = fsig(a1[2]), gG = ftanh(a2[2]), gO = fsig(a3[2]);
                    float cn = gF * c0f[cown][cb + 2] + gi * gG;
                    c0f[cown][cb + 2] = cn;
                    hi = (u32)f2h(gO * ftanh(cn));
                }
                {
                    float gi = fsig(a0[3]), gF = fsig(a1[3]), gG = ftanh(a2[3]), gO = fsig(a3[3]);
                    float cn = gF * c0f[cown][cb + 3] + gi * gG;
                    c0f[cown][cb + 3] = cn;
                    hi |= (u32)f2h(gO * ftanh(cn)) << 16;
                }
                uint2 pk; pk.x = lo; pk.y = hi;
                *(uint2*)&h0h[p ^ 1][cown][cb] = pk;
            }
        }
        lds_barrier();

        // ---- G (MFMA, gate-interleaved) + in-register lstm1 update ----
        {
            const u16* pw = pG + (size_t)wv * 32 * 512 + (size_t)l * 8;
            f32x4 a0 = *(const f32x4*)&bsum1s[0 * 128 + wv * 16 + kg * 4];
            f32x4 a1 = *(const f32x4*)&bsum1s[1 * 128 + wv * 16 + kg * 4];
            f32x4 a2 = *(const f32x4*)&bsum1s[2 * 128 + wv * 16 + kg * 4];
            f32x4 a3 = *(const f32x4*)&bsum1s[3 * 128 + wv * 16 + kg * 4];
            #pragma unroll
            for (int ks = 0; ks < 2; ++ks) {            // prefetched frags (h0new)
                f16x8 b = *(const f16x8*)&h0h[p ^ 1][c4][ks * 32 + kg * 8];
                a0 = MFMA16(gw0[ks * 4 + 0], b, a0);
                a1 = MFMA16(gw0[ks * 4 + 1], b, a1);
                a2 = MFMA16(gw0[ks * 4 + 2], b, a2);
                a3 = MFMA16(gw0[ks * 4 + 3], b, a3);
            }
            #pragma unroll
            for (int ks = 2; ks < 8; ++ks) {            // streamed frags
                const u16* bp = (ks < 4) ? &h0h[p ^ 1][c4][ks * 32 + kg * 8]
                                         : &h1h[p][c4][(ks - 4) * 32 + kg * 8];
                f16x8 b = *(const f16x8*)bp;
                a0 = MFMA16(*(const f16x8*)(pw + (ks * 4 + 0) * 512), b, a0);
                a1 = MFMA16(*(const f16x8*)(pw + (ks * 4 + 1) * 512), b, a1);
                a2 = MFMA16(*(const f16x8*)(pw + (ks * 4 + 2) * 512), b, a2);
                a3 = MFMA16(*(const f16x8*)(pw + (ks * 4 + 3) * 512), b, a3);
            }
            if (cown < 4) {
                int cb = wv * 16 + kg * 4;
                u32 lo, hi, clo, chi;
                {
                    float gi = fsig(a0[0]), gF = fsig(a1[0]), gG = ftanh(a2[0]), gO = fsig(a3[0]);
                    float cn = gF * c1f[cown][cb + 0] + gi * gG;
                    c1f[cown][cb + 0] = cn;
                    clo = (u32)f2h(cn);
                    lo  = (u32)f2h(gO * ftanh(cn));
                }
                {
                    float gi = fsig(a0[1]), gF = fsig(a1[1]), gG = ftanh(a2[1]), gO = fsig(a3[1]);
                    float cn = gF * c1f[cown][cb + 1] + gi * gG;
                    c1f[cown][cb + 1] = cn;
                    clo |= (u32)f2h(cn) << 16;
                    lo  |= (u32)f2h(gO * ftanh(cn)) << 16;
                }
                {
                    float gi = fsig(a0[2]), gF = fsig(a1[2]), gG = ftanh(a2[2]), gO = fsig(a3[2]);
                    float cn = gF * c1f[cown][cb + 2] + gi * gG;
                    c1f[cown][cb + 2] = cn;
                    chi = (u32)f2h(cn);
                    hi  = (u32)f2h(gO * ftanh(cn));
                }
                {
                    float gi = fsig(a0[3]), gF = fsig(a1[3]), gG = ftanh(a2[3]), gO = fsig(a3[3]);
                    float cn = gF * c1f[cown][cb + 3] + gi * gG;
                    c1f[cown][cb + 3] = cn;
                    chi |= (u32)f2h(cn) << 16;
                    hi  |= (u32)f2h(gO * ftanh(cn)) << 16;
                }
                uint2 pk; pk.x = lo; pk.y = hi;
                *(uint2*)&h1h[p ^ 1][cown][cb] = pk;
                uint2 ck; ck.x = clo; ck.y = chi;
                *(uint2*)&c1h[cown][cb] = ck;
            }
        }
        lds_barrier();
    }

    // ---- epilogue: y = relu([h1,ctx] @ fcf_w.T + fcf_b); final h1 in side 0 ----
    if (tid < 256) {
        int f = tid >> 2, bb = tid & 3;
        const float* wr = fcfw + (size_t)f * 256;
        float acc = fcfb[f];
        #pragma unroll 4
        for (int k4 = 0; k4 < 32; ++k4) {
            float4 w = *(const float4*)(wr + k4 * 4);
            acc += w.x * h2f(h1h[0][bb][k4 * 4 + 0]) + w.y * h2f(h1h[0][bb][k4 * 4 + 1])
                 + w.z * h2f(h1h[0][bb][k4 * 4 + 2]) + w.w * h2f(h1h[0][bb][k4 * 4 + 3]);
        }
        #pragma unroll 4
        for (int k4 = 0; k4 < 32; ++k4) {
            float4 w = *(const float4*)(wr + 128 + k4 * 4);
            acc += w.x * h2f(ctyh[bb][k4 * 4 + 0]) + w.y * h2f(ctyh[bb][k4 * 4 + 1])
                 + w.z * h2f(ctyh[bb][k4 * 4 + 2]) + w.w * h2f(ctyh[bb][k4 * 4 + 3]);
        }
        out[(size_t)(b0 + bb) * FF + f] = fmaxf(acc, 0.f);
    }
}

extern "C" void kernel_launch(void* const* d_in, const int* in_sizes, int n_in,
                              void* d_out, int out_size, void* d_ws, size_t ws_size,
                              hipStream_t stream) {
    (void)in_sizes; (void)n_in; (void)out_size; (void)ws_size;
    const float* X    = (const float*)d_in[0];
    const float* yp   = (const float*)d_in[1];
    const float* w1   = (const float*)d_in[2];
    const float* b1   = (const float*)d_in[3];
    const float* w2   = (const float*)d_in[4];
    const float* b2   = (const float*)d_in[5];
    const float* fcw  = (const float*)d_in[6];
    const float* fcb  = (const float*)d_in[7];
    const float* bng  = (const float*)d_in[8];
    const float* bnb  = (const float*)d_in[9];
    const float* bnm  = (const float*)d_in[10];
    const float* bnv  = (const float*)d_in[11];
    const float* wih0 = (const float*)d_in[12];
    const float* whh0 = (const float*)d_in[13];
    const float* bih0 = (const float*)d_in[14];
    const float* bhh0 = (const float*)d_in[15];
    const float* wih1 = (const float*)d_in[16];
    const float* whh1 = (const float*)d_in[17];
    const float* bih1 = (const float*)d_in[18];
    const float* bhh1 = (const float*)d_in[19];
    const float* fcfw = (const float*)d_in[20];
    const float* fcfb = (const float*)d_in[21];
    float* out = (float*)d_out;

    // fragment-packed fp16 weights in d_ws
    u16* pA = (u16*)d_ws;              // 32768
    u16* pE = pA + 32768;              // 12288
    u16* pF = pE + 12288;              // 98304
    u16* pG = pF + 98304;              // 131072  (total 274432 u16 = 549 KB)

    packA_k<<<dim3(32768 / 256), dim3(256), 0, stream>>>(w1, pA);
    packE_k<<<dim3(12288 / 256), dim3(256), 0, stream>>>(fcw, pE);
    packF_k<<<dim3(98304 / 256), dim3(256), 0, stream>>>(wih0, whh0, pF);
    packG_k<<<dim3(131072 / 256), dim3(256), 0, stream>>>(wih1, whh1, pG);

    decoder_kernel<<<dim3(1024 / NB), dim3(NTHR), 0, stream>>>(
        X, yp, w1, b1, w2, b2, fcb, bng, bnb, bnm, bnv,
        bih0, bhh0, bih1, bhh1, fcfw, fcfb, pA, pE, pF, pG, out);
}

// Round 16
// 829.551 us; speedup vs baseline: 1.6315x; 1.0016x over previous
//
#include <hip/hip_runtime.h>
#include <math.h>

#define TT 50
#define MM 128
#define PP 128
#define FF 64
#define NB 4
#define NTHR 512
#define BN_EPS 1e-5f

typedef unsigned int   u32;
typedef unsigned short u16;
typedef _Float16 f16x8 __attribute__((ext_vector_type(8)));
typedef float    f32x4 __attribute__((ext_vector_type(4)));

#define MFMA16(a, b, c) __builtin_amdgcn_mfma_f32_16x16x32_f16((a), (b), (c), 0, 0, 0)

__device__ __forceinline__ float fsig(float x)  { return 1.0f / (1.0f + __expf(-x)); }
__device__ __forceinline__ float ftanh(float x) { return 1.0f - 2.0f / (__expf(2.0f * x) + 1.0f); }
__device__ __forceinline__ u16 f2h(float x) { _Float16 h = (_Float16)x; u16 r; __builtin_memcpy(&r, &h, 2); return r; }
__device__ __forceinline__ float h2f(u16 u) { _Float16 h; __builtin_memcpy(&h, &u, 2); return (float)h; }

// LDS-only barrier (R9 win): drains lgkmcnt but NOT vmcnt, so global weight
// loads stay in flight across phase boundaries.
__device__ __forceinline__ void lds_barrier() {
    asm volatile("s_waitcnt lgkmcnt(0)\n\ts_barrier" ::: "memory");
}

// ---------------- weight fragment pre-pack (fp16, MFMA A-operand order) ----------
__global__ __launch_bounds__(256) void packA_k(const float* __restrict__ w1, u16* __restrict__ dst) {
    int i = blockIdx.x * 256 + threadIdx.x;
    if (i >= 8 * 8 * 64 * 8) return;                    // 32768
    int j = i & 7, l = (i >> 3) & 63, ks = (i >> 9) & 7, tile = i >> 12;
    int row = tile * 16 + (l & 15);
    int k = ks * 32 + ((l >> 4) & 3) * 8 + j;           // k<256 -> [w1_d | w1_c]
    dst[i] = f2h(w1[row * 384 + k]);
}
__global__ __launch_bounds__(256) void packE_k(const float* __restrict__ fcw, u16* __restrict__ dst) {
    int i = blockIdx.x * 256 + threadIdx.x;
    if (i >= 4 * 6 * 64 * 8) return;                    // 12288
    int j = i & 7, l = (i >> 3) & 63, r = i >> 9;
    int ks = r % 6, tile = r / 6;
    int row = tile * 16 + (l & 15);
    int k = ks * 32 + ((l >> 4) & 3) * 8 + j;           // k<192 -> [ctx | yt]
    dst[i] = f2h(fcw[row * 192 + k]);
}
// pF/pG: frag index = wv*NF + ks*4 + g, gate-interleaved rows (R9 win).
__global__ __launch_bounds__(256) void packF_k(const float* __restrict__ wih0, const float* __restrict__ whh0,
                                               u16* __restrict__ dst) {
    int i = blockIdx.x * 256 + threadIdx.x;
    if (i >= 8 * 24 * 64 * 8) return;                   // 98304
    int j = i & 7, l = (i >> 3) & 63, rem = i >> 9;     // rem 0..191
    int wv = rem / 24, t = rem % 24, ks = t >> 2, g = t & 3;
    int row = g * 128 + wv * 16 + (l & 15);             // gate-interleaved
    int k = ks * 32 + ((l >> 4) & 3) * 8 + j;           // k<192: [ytil(64) | h0(128)]
    float v = (k < 64) ? wih0[row * 64 + k] : whh0[row * 128 + (k - 64)];
    dst[i] = f2h(v);
}
__global__ __launch_bounds__(256) void packG_k(const float* __restrict__ wih1, const float* __restrict__ whh1,
                                               u16* __restrict__ dst) {
    int i = blockIdx.x * 256 + threadIdx.x;
    if (i >= 8 * 32 * 64 * 8) return;                   // 131072
    int j = i & 7, l = (i >> 3) & 63, rem = i >> 9;     // rem 0..255
    int wv = rem >> 5, t = rem & 31, ks = t >> 2, g = t & 3;
    int row = g * 128 + wv * 16 + (l & 15);             // gate-interleaved
    int k = ks * 32 + ((l >> 4) & 3) * 8 + j;           // k<256: [h0new(128) | h1old(128)]
    float v = (k < 128) ? wih1[row * 128 + k] : whh1[row * 128 + (k - 128)];
    dst[i] = f2h(v);
}

// ---------------- main fused decoder (R15 + transposed X tile for phase D) ------
__global__ __launch_bounds__(NTHR, 2) void decoder_kernel(
    const float* __restrict__ X,      // (B,T,M) f32
    const float* __restrict__ yprev,  // (B,T,F) f32
    const float* __restrict__ w1,     // (128,384) f32 (xp prologue only)
    const float* __restrict__ b1,
    const float* __restrict__ w2,
    const float* __restrict__ b2,
    const float* __restrict__ fcb,
    const float* __restrict__ bng,
    const float* __restrict__ bnb,
    const float* __restrict__ bnm,
    const float* __restrict__ bnv,
    const float* __restrict__ bih0,
    const float* __restrict__ bhh0,
    const float* __restrict__ bih1,
    const float* __restrict__ bhh1,
    const float* __restrict__ fcfw,   // (64,256) f32 (epilogue)
    const float* __restrict__ fcfb,
    const u16* __restrict__ pA,       // packed frags
    const u16* __restrict__ pE,
    const u16* __restrict__ pF,
    const u16* __restrict__ pG,
    float* __restrict__ out)          // (B,64)
{
    // XhT: X transposed [m][t] so D reads 4 t per uint2 (13 reads vs 50 scalar).
    // Row stride 120B = 30 banks, gcd(30,32)=2 -> 2-way conflict (free, m136).
    // R13's regression was the gw1 register deepening (spill), not this layout.
    __shared__ __align__(16) u16   XhT[NB][MM][60];      // 61.4 KB
    __shared__ __align__(16) u16   xph[NB][TT][140];     // fp16 x_proj
    __shared__ __align__(16) u16   h0h[2][NB][144];
    __shared__ __align__(16) u16   h1h[2][NB][144];
    __shared__ __align__(16) u16   c1h[NB][144];
    __shared__ __align__(16) u16   ytilh[NB][72];
    __shared__ __align__(16) u16   ctyh[NB][200];        // [ctx(128) | yt(64)]
    __shared__ __align__(16) float spf[NB][132];
    __shared__ __align__(16) float c0f[NB][132], c1f[NB][132];
    __shared__ __align__(16) float scs[NB][68];
    __shared__ __align__(16) float b1s[128], w2s[128];
    __shared__ __align__(16) float fck0s[FF], fck1s[FF];
    __shared__ __align__(16) float bsum0s[512], bsum1s[512];

    const int tid = threadIdx.x;
    const int b0 = blockIdx.x * NB;
    const int wv = tid >> 6, l = tid & 63;
    const int kg = (l >> 4) & 3;      // k-group within wave
    const int c4 = l & 3;             // batch col (duplicated to cols 4-15)
    const int cown = l & 15;          // C-frag col; valid batch iff <4

    // ---- prologue: X -> fp16 transposed LDS ----
    for (int i4 = tid; i4 < NB * TT * 32; i4 += NTHR) {
        int bb = i4 / (TT * 32);
        int r  = i4 % (TT * 32);
        int t = r >> 5, m4 = (r & 31) * 4;
        float4 v = ((const float4*)(X + (size_t)(b0 + bb) * TT * MM))[r];
        XhT[bb][m4 + 0][t] = f2h(v.x);
        XhT[bb][m4 + 1][t] = f2h(v.y);
        XhT[bb][m4 + 2][t] = f2h(v.z);
        XhT[bb][m4 + 3][t] = f2h(v.w);
    }
    {   // zero pads: XhT t=50..51 (D's uint2 tail) and scs t=50..51 (f32x4 tail)
        int bb = tid >> 7, m = tid & 127;
        XhT[bb][m][50] = 0; XhT[bb][m][51] = 0;
    }
    if (tid < NB * 4) scs[tid >> 2][48 + (tid & 3) + 2] = 0.f;  // scs[bb][50..53]
    for (int i = tid; i < NB * 144; i += NTHR) {
        int bb = i / 144, k = i % 144;
        h0h[0][bb][k] = 0; h0h[1][bb][k] = 0;
        h1h[0][bb][k] = 0; h1h[1][bb][k] = 0;
        c1h[bb][k] = 0;
        if (k < 132) { c0f[bb][k] = 0.f; c1f[bb][k] = 0.f; }
    }
    if (tid < 128) { b1s[tid] = b1[tid]; w2s[tid] = w2[tid]; }
    else if (tid < 192) {
        int f = tid - 128;
        float k1 = rsqrtf(bnv[f] + BN_EPS) * bng[f];
        fck1s[f] = k1;
        fck0s[f] = (fcb[f] - bnm[f]) * k1 + bnb[f];
    }
    bsum0s[tid] = bih0[tid] + bhh0[tid];
    bsum1s[tid] = bih1[tid] + bhh1[tid];

    // ---- phase-B ownership + xp prologue (f32 math from global X -> fp16 LDS) ----
    const int bq = tid >> 7, rr = tid & 127;
    const bool own = rr < 2 * TT;
    const int tq = rr >> 1, qq = rr & 1;
    const float b2v = b2[0];

    if (own) {
        float xf[64];
        #pragma unroll
        for (int n = 0; n < 64; ++n) xf[n] = 0.f;
        const float* Xrow = X + ((size_t)(b0 + bq) * TT + tq) * MM;
        for (int m4 = 0; m4 < 32; ++m4) {
            float4 xv = *(const float4*)(Xrow + m4 * 4);
            #pragma unroll
            for (int n = 0; n < 64; ++n) {
                float4 w = *(const float4*)(w1 + (size_t)(qq * 64 + n) * 384 + 256 + m4 * 4);
                xf[n] += xv.x * w.x + xv.y * w.y + xv.z * w.z + xv.w * w.w;
            }
        }
        #pragma unroll
        for (int j = 0; j < 32; ++j) {
            u32 pk = (u32)f2h(xf[2 * j]) | ((u32)f2h(xf[2 * j + 1]) << 16);
            *(u32*)&xph[bq][tq][qq * 64 + 2 * j] = pk;
        }
    }
    __syncthreads();   // prologue touched global->LDS; full sync once

    for (int ts = 0; ts < TT; ++ts) {
        const int p = ts & 1;

        // ---- A (MFMA): sp = w1_dc @ [h1|c1] ----
        {
            f32x4 acc = *(const f32x4*)&b1s[wv * 16 + kg * 4];
            const u16* abase = pA + (size_t)(wv * 8) * 512 + (size_t)l * 8;
            #pragma unroll
            for (int ks = 0; ks < 8; ++ks) {
                f16x8 a = *(const f16x8*)(abase + ks * 512);
                const u16* bp = (ks < 4) ? &h1h[p][c4][ks * 32 + kg * 8]
                                         : &c1h[c4][(ks - 4) * 32 + kg * 8];
                acc = MFMA16(a, *(const f16x8*)bp, acc);
            }
            if (cown < 4) *(f32x4*)&spf[cown][wv * 16 + kg * 4] = acc;
        }
        // prefetch E frags now; they ride across the next 4 LDS barriers
        f16x8 ew[6];
        if (wv < 4) {
            const u16* abase = pE + (size_t)(wv * 6) * 512 + (size_t)l * 8;
            #pragma unroll
            for (int ks = 0; ks < 6; ++ks) ew[ks] = *(const f16x8*)(abase + ks * 512);
        }
        lds_barrier();

        // ---- B (VALU): score[t] = sum_n tanh(xp+sp)*w2, vectorized LDS reads ----
        if (own) {
            float acc = 0.f;
            #pragma unroll
            for (int jb = 0; jb < 8; ++jb) {
                int n = qq * 64 + jb * 8;
                uint4 xv  = *(const uint4*)&xph[bq][tq][n];
                f32x4 sp0 = *(const f32x4*)&spf[bq][n];
                f32x4 sp1 = *(const f32x4*)&spf[bq][n + 4];
                f32x4 wv0 = *(const f32x4*)&w2s[n];
                f32x4 wv1 = *(const f32x4*)&w2s[n + 4];
                acc += ftanh(h2f((u16)(xv.x & 0xffffu)) + sp0[0]) * wv0[0];
                acc += ftanh(h2f((u16)(xv.x >> 16))     + sp0[1]) * wv0[1];
                acc += ftanh(h2f((u16)(xv.y & 0xffffu)) + sp0[2]) * wv0[2];
                acc += ftanh(h2f((u16)(xv.y >> 16))     + sp0[3]) * wv0[3];
                acc += ftanh(h2f((u16)(xv.z & 0xffffu)) + sp1[0]) * wv1[0];
                acc += ftanh(h2f((u16)(xv.z >> 16))     + sp1[1]) * wv1[1];
                acc += ftanh(h2f((u16)(xv.w & 0xffffu)) + sp1[2]) * wv1[2];
                acc += ftanh(h2f((u16)(xv.w >> 16))     + sp1[3]) * wv1[3];
            }
            acc += __shfl_xor(acc, 1);
            if (qq == 0) scs[bq][tq] = acc + b2v;
        }
        lds_barrier();

        // ---- C: softmax (4 waves) + y_t load ----
        if (tid < 256) {
            int b = tid >> 6, t = tid & 63;
            float v = (t < TT) ? scs[b][t] : -1e30f;
            float mx = v;
            #pragma unroll
            for (int o = 32; o; o >>= 1) mx = fmaxf(mx, __shfl_xor(mx, o));
            float e = (t < TT) ? __expf(v - mx) : 0.f;
            float s = e;
            #pragma unroll
            for (int o = 32; o; o >>= 1) s += __shfl_xor(s, o);
            if (t < TT) scs[b][t] = e / s;
        } else {
            int i = tid - 256; int bb = i >> 6, f = i & 63;
            ctyh[bb][128 + f] = f2h(yprev[((size_t)(b0 + bb) * TT + ts) * FF + f]);
        }
        lds_barrier();

        // ---- D (VALU): ctx[m] = sum_t beta[t]*X[t][m] via XhT (13 uint2 + 13 f32x4);
        //      prefetch first 8 F frags ----
        f16x8 fw0[8];
        {
            const u16* pw = pF + (size_t)wv * 24 * 512 + (size_t)l * 8;
            #pragma unroll
            for (int q = 0; q < 8; ++q) fw0[q] = *(const f16x8*)(pw + q * 512);
        }
        {
            int bb = tid >> 7, m = tid & 127;
            float acc = 0.f;
            #pragma unroll
            for (int t4 = 0; t4 < 13; ++t4) {
                uint2 xv = *(const uint2*)&XhT[bb][m][t4 * 4];
                f32x4 sc = *(const f32x4*)&scs[bb][t4 * 4];
                acc += sc[0] * h2f((u16)(xv.x & 0xffffu));
                acc += sc[1] * h2f((u16)(xv.x >> 16));
                acc += sc[2] * h2f((u16)(xv.y & 0xffffu));
                acc += sc[3] * h2f((u16)(xv.y >> 16));
            }
            ctyh[bb][m] = f2h(acc);
        }
        lds_barrier();

        // ---- E (MFMA, waves 0-3): z = fcw @ [ctx|yt]; batchnorm -> ytil ----
        if (wv < 4) {
            f32x4 acc = {0.f, 0.f, 0.f, 0.f};
            #pragma unroll
            for (int ks = 0; ks < 6; ++ks) {
                f16x8 b = *(const f16x8*)&ctyh[c4][ks * 32 + kg * 8];
                acc = MFMA16(ew[ks], b, acc);
            }
            if (cown < 4) {
                int row = wv * 16 + kg * 4;
                f32x4 k1 = *(const f32x4*)&fck1s[row];
                f32x4 k0 = *(const f32x4*)&fck0s[row];
                #pragma unroll
                for (int r = 0; r < 4; ++r)
                    ytilh[cown][row + r] = f2h(acc[r] * k1[r] + k0[r]);
            }
        }
        lds_barrier();

        // ---- F (MFMA, gate-interleaved) + in-register lstm0 update;
        //      prefetch first 8 G frags (fw0 dead after its MFMAs) ----
        f16x8 gw0[8];
        {
            const u16* pw = pF + (size_t)wv * 24 * 512 + (size_t)l * 8;
            f32x4 a0 = *(const f32x4*)&bsum0s[0 * 128 + wv * 16 + kg * 4];
            f32x4 a1 = *(const f32x4*)&bsum0s[1 * 128 + wv * 16 + kg * 4];
            f32x4 a2 = *(const f32x4*)&bsum0s[2 * 128 + wv * 16 + kg * 4];
            f32x4 a3 = *(const f32x4*)&bsum0s[3 * 128 + wv * 16 + kg * 4];
            #pragma unroll
            for (int ks = 0; ks < 2; ++ks) {            // prefetched frags
                f16x8 b = *(const f16x8*)&ytilh[c4][ks * 32 + kg * 8];
                a0 = MFMA16(fw0[ks * 4 + 0], b, a0);
                a1 = MFMA16(fw0[ks * 4 + 1], b, a1);
                a2 = MFMA16(fw0[ks * 4 + 2], b, a2);
                a3 = MFMA16(fw0[ks * 4 + 3], b, a3);
            }
            #pragma unroll
            for (int ks = 2; ks < 6; ++ks) {            // streamed frags
                f16x8 b = *(const f16x8*)&h0h[p][c4][(ks - 2) * 32 + kg * 8];
                a0 = MFMA16(*(const f16x8*)(pw + (ks * 4 + 0) * 512), b, a0);
                a1 = MFMA16(*(const f16x8*)(pw + (ks * 4 + 1) * 512), b, a1);
                a2 = MFMA16(*(const f16x8*)(pw + (ks * 4 + 2) * 512), b, a2);
                a3 = MFMA16(*(const f16x8*)(pw + (ks * 4 + 3) * 512), b, a3);
            }
            {   // G prefetch: first 8 frags (ks 0..1), issued while F finishes
                const u16* pwg = pG + (size_t)wv * 32 * 512 + (size_t)l * 8;
                #pragma unroll
                for (int q = 0; q < 8; ++q) gw0[q] = *(const f16x8*)(pwg + q * 512);
            }
            if (cown < 4) {                             // a0..a3 = i,f,g,o of own cells
                int cb = wv * 16 + kg * 4;
                u32 lo, hi;
                {
                    float gi = fsig(a0[0]), gF = fsig(a1[0]), gG = ftanh(a2[0]), gO = fsig(a3[0]);
                    float cn = gF * c0f[cown][cb + 0] + gi * gG;
                    c0f[cown][cb + 0] = cn;
                    lo = (u32)f2h(gO * ftanh(cn));
                }
                {
                    float gi = fsig(a0[1]), gF = fsig(a1[1]), gG = ftanh(a2[1]), gO = fsig(a3[1]);
                    float cn = gF * c0f[cown][cb + 1] + gi * gG;
                    c0f[cown][cb + 1] = cn;
                    lo |= (u32)f2h(gO * ftanh(cn)) << 16;
                }
                {
                    float gi = fsig(a0[2]), gF = fsig(a1[2]), gG = ftanh(a2[2]), gO = fsig(a3[2]);
                    float cn = gF * c0f[cown][cb + 2] + gi * gG;
                    c0f[cown][cb + 2] = cn;
                    hi = (u32)f2h(gO * ftanh(cn));
                }
                {
                    float gi = fsig(a0[3]), gF = fsig(a1[3]), gG = ftanh(a2[3]), gO = fsig(a3[3]);
                    float cn = gF * c0f[cown][cb + 3] + gi * gG;
                    c0f[cown][cb + 3] = cn;
                    hi |= (u32)f2h(gO * ftanh(cn)) << 16;
                }
                uint2 pk; pk.x = lo; pk.y = hi;
                *(uint2*)&h0h[p ^ 1][cown][cb] = pk;
            }
        }
        lds_barrier();

        // ---- G (MFMA, gate-interleaved) + in-register lstm1 update ----
        {
            const u16* pw = pG + (size_t)wv * 32 * 512 + (size_t)l * 8;
            f32x4 a0 = *(const f32x4*)&bsum1s[0 * 128 + wv * 16 + kg * 4];
            f32x4 a1 = *(const f32x4*)&bsum1s[1 * 128 + wv * 16 + kg * 4];
            f32x4 a2 = *(const f32x4*)&bsum1s[2 * 128 + wv * 16 + kg * 4];
            f32x4 a3 = *(const f32x4*)&bsum1s[3 * 128 + wv * 16 + kg * 4];
            #pragma unroll
            for (int ks = 0; ks < 2; ++ks) {            // prefetched frags (h0new)
                f16x8 b = *(const f16x8*)&h0h[p ^ 1][c4][ks * 32 + kg * 8];
                a0 = MFMA16(gw0[ks * 4 + 0], b, a0);
                a1 = MFMA16(gw0[ks * 4 + 1], b, a1);
                a2 = MFMA16(gw0[ks * 4 + 2], b, a2);
                a3 = MFMA16(gw0[ks * 4 + 3], b, a3);
            }
            #pragma unroll
            for (int ks = 2; ks < 8; ++ks) {            // streamed frags
                const u16* bp = (ks < 4) ? &h0h[p ^ 1][c4][ks * 32 + kg * 8]
                                         : &h1h[p][c4][(ks - 4) * 32 + kg * 8];
                f16x8 b = *(const f16x8*)bp;
                a0 = MFMA16(*(const f16x8*)(pw + (ks * 4 + 0) * 512), b, a0);
                a1 = MFMA16(*(const f16x8*)(pw + (ks * 4 + 1) * 512), b, a1);
                a2 = MFMA16(*(const f16x8*)(pw + (ks * 4 + 2) * 512), b, a2);
                a3 = MFMA16(*(const f16x8*)(pw + (ks * 4 + 3) * 512), b, a3);
            }
            if (cown < 4) {
                int cb = wv * 16 + kg * 4;
                u32 lo, hi, clo, chi;
                {
                    float gi = fsig(a0[0]), gF = fsig(a1[0]), gG = ftanh(a2[0]), gO = fsig(a3[0]);
                    float cn = gF * c1f[cown][cb + 0] + gi * gG;
                    c1f[cown][cb + 0] = cn;
                    clo = (u32)f2h(cn);
                    lo  = (u32)f2h(gO * ftanh(cn));
                }
                {
                    float gi = fsig(a0[1]), gF = fsig(a1[1]), gG = ftanh(a2[1]), gO = fsig(a3[1]);
                    float cn = gF * c1f[cown][cb + 1] + gi * gG;
                    c1f[cown][cb + 1] = cn;
                    clo |= (u32)f2h(cn) << 16;
                    lo  |= (u32)f2h(gO * ftanh(cn)) << 16;
                }
                {
                    float gi = fsig(a0[2]), gF = fsig(a1[2]), gG = ftanh(a2[2]), gO = fsig(a3[2]);
                    float cn = gF * c1f[cown][cb + 2] + gi * gG;
                    c1f[cown][cb + 2] = cn;
                    chi = (u32)f2h(cn);
                    hi  = (u32)f2h(gO * ftanh(cn));
                }
                {
                    float gi = fsig(a0[3]), gF = fsig(a1[3]), gG = ftanh(a2[3]), gO = fsig(a3[3]);
                    float cn = gF * c1f[cown][cb + 3] + gi * gG;
                    c1f[cown][cb + 3] = cn;
                    chi |= (u32)f2h(cn) << 16;
                    hi  |= (u32)f2h(gO * ftanh(cn)) << 16;
                }
                uint2 pk; pk.x = lo; pk.y = hi;
                *(uint2*)&h1h[p ^ 1][cown][cb] = pk;
                uint2 ck; ck.x = clo; ck.y = chi;
                *(uint2*)&c1h[cown][cb] = ck;
            }
        }
        lds_barrier();
    }

    // ---- epilogue: y = relu([h1,ctx] @ fcf_w.T + fcf_b); final h1 in side 0 ----
    if (tid < 256) {
        int f = tid >> 2, bb = tid & 3;
        const float* wr = fcfw + (size_t)f * 256;
        float acc = fcfb[f];
        #pragma unroll 4
        for (int k4 = 0; k4 < 32; ++k4) {
            float4 w = *(const float4*)(wr + k4 * 4);
            acc += w.x * h2f(h1h[0][bb][k4 * 4 + 0]) + w.y * h2f(h1h[0][bb][k4 * 4 + 1])
                 + w.z * h2f(h1h[0][bb][k4 * 4 + 2]) + w.w * h2f(h1h[0][bb][k4 * 4 + 3]);
        }
        #pragma unroll 4
        for (int k4 = 0; k4 < 32; ++k4) {
            float4 w = *(const float4*)(wr + 128 + k4 * 4);
            acc += w.x * h2f(ctyh[bb][k4 * 4 + 0]) + w.y * h2f(ctyh[bb][k4 * 4 + 1])
                 + w.z * h2f(ctyh[bb][k4 * 4 + 2]) + w.w * h2f(ctyh[bb][k4 * 4 + 3]);
        }
        out[(size_t)(b0 + bb) * FF + f] = fmaxf(acc, 0.f);
    }
}

extern "C" void kernel_launch(void* const* d_in, const int* in_sizes, int n_in,
                              void* d_out, int out_size, void* d_ws, size_t ws_size,
                              hipStream_t stream) {
    (void)in_sizes; (void)n_in; (void)out_size; (void)ws_size;
    const float* X    = (const float*)d_in[0];
    const float* yp   = (const float*)d_in[1];
    const float* w1   = (const float*)d_in[2];
    const float* b1   = (const float*)d_in[3];
    const float* w2   = (const float*)d_in[4];
    const float* b2   = (const float*)d_in[5];
    const float* fcw  = (const float*)d_in[6];
    const float* fcb  = (const float*)d_in[7];
    const float* bng  = (const float*)d_in[8];
    const float* bnb  = (const float*)d_in[9];
    const float* bnm  = (const float*)d_in[10];
    const float* bnv  = (const float*)d_in[11];
    const float* wih0 = (const float*)d_in[12];
    const float* whh0 = (const float*)d_in[13];
    const float* bih0 = (const float*)d_in[14];
    const float* bhh0 = (const float*)d_in[15];
    const float* wih1 = (const float*)d_in[16];
    const float* whh1 = (const float*)d_in[17];
    const float* bih1 = (const float*)d_in[18];
    const float* bhh1 = (const float*)d_in[19];
    const float* fcfw = (const float*)d_in[20];
    const float* fcfb = (const float*)d_in[21];
    float* out = (float*)d_out;

    // fragment-packed fp16 weights in d_ws
    u16* pA = (u16*)d_ws;              // 32768
    u16* pE = pA + 32768;              // 12288
    u16* pF = pE + 12288;              // 98304
    u16* pG = pF + 98304;              // 131072  (total 274432 u16 = 549 KB)

    packA_k<<<dim3(32768 / 256), dim3(256), 0, stream>>>(w1, pA);
    packE_k<<<dim3(12288 / 256), dim3(256), 0, stream>>>(fcw, pE);
    packF_k<<<dim3(98304 / 256), dim3(256), 0, stream>>>(wih0, whh0, pF);
    packG_k<<<dim3(131072 / 256), dim3(256), 0, stream>>>(wih1, whh1, pG);

    decoder_kernel<<<dim3(1024 / NB), dim3(NTHR), 0, stream>>>(
        X, yp, w1, b1, w2, b2, fcb, bng, bnb, bnm, bnv,
        bih0, bhh0, bih1, bhh1, fcfw, fcfb, pA, pE, pF, pG, out);
}